// Round 1
// baseline (198.042 us; speedup 1.0000x reference)
//
#include <hip/hip_runtime.h>
#include <hip/hip_bf16.h>

// MeanEmbedding: out[b,d] = (1/len[b]) * sum_{s<len[b]} xs[b,s,d]
// xs: [B=16, S=4096, D=512] fp32, xs_len: [B] int, out: [B, D] fp32.
//
// Strategy: memory-bound streaming sum. Grid (B, CHUNKS) blocks; each block
// reduces a 64-row slab of one sequence across the full D width (128 lanes
// x float4 = 512 floats/row, fully coalesced). Partial results are scaled
// by 1/len and atomically added into the zeroed output.

#define THREADS 128       // D/4 = 512/4 = 128 float4 lanes per row
#define CHUNKS  64        // S/CHUNKS = 64 rows per block

__global__ __launch_bounds__(THREADS) void mean_embed_kernel(
    const float* __restrict__ xs,
    const int*   __restrict__ xs_len,
    float*       __restrict__ out,
    int S, int D)
{
    const int b     = blockIdx.x;
    const int chunk = blockIdx.y;
    const int L     = xs_len[b];

    const int rows_per_blk = S / CHUNKS;      // 64
    const int row0 = chunk * rows_per_blk;
    if (row0 >= L) return;                    // slab entirely masked out
    const int row1 = min(row0 + rows_per_blk, L);

    const int tid = threadIdx.x;              // 0..127 -> float4 column
    const int d4  = D >> 2;                   // 128

    const float4* base = (const float4*)(xs + (size_t)b * S * D);

    float4 acc = make_float4(0.f, 0.f, 0.f, 0.f);
    for (int s = row0; s < row1; ++s) {
        float4 v = base[(size_t)s * d4 + tid];
        acc.x += v.x; acc.y += v.y; acc.z += v.z; acc.w += v.w;
    }

    const float inv = 1.0f / (float)L;
    float* o = out + (size_t)b * D + tid * 4;
    atomicAdd(o + 0, acc.x * inv);
    atomicAdd(o + 1, acc.y * inv);
    atomicAdd(o + 2, acc.z * inv);
    atomicAdd(o + 3, acc.w * inv);
}

extern "C" void kernel_launch(void* const* d_in, const int* in_sizes, int n_in,
                              void* d_out, int out_size, void* d_ws, size_t ws_size,
                              hipStream_t stream) {
    const float* xs     = (const float*)d_in[0];
    const int*   xs_len = (const int*)d_in[1];
    float*       out    = (float*)d_out;

    const int B = in_sizes[1];                 // 16
    const int total = in_sizes[0];             // B*S*D
    const int D = 512;
    const int S = total / (B * D);             // 4096

    // d_out is poisoned to 0xAA before every call -> zero it (capture-safe).
    hipMemsetAsync(d_out, 0, (size_t)out_size * sizeof(float), stream);

    dim3 grid(B, CHUNKS);
    mean_embed_kernel<<<grid, THREADS, 0, stream>>>(xs, xs_len, out, S, D);
}